// Round 5
// baseline (936.552 us; speedup 1.0000x reference)
//
#include <hip/hip_runtime.h>

using u16 = unsigned short;
using u32 = unsigned int;

typedef __attribute__((ext_vector_type(8))) short bf16x8;   // 8 bf16 (MFMA frag)
typedef __attribute__((ext_vector_type(4))) float f32x4;    // MFMA acc
typedef __attribute__((ext_vector_type(8))) u16 u16x8;

// ---------- helpers ----------
static __device__ __forceinline__ float b2f(u16 u) {
  return __uint_as_float((u32)u << 16);
}
static __device__ __forceinline__ u16 f2b(float f) {  // RNE bf16
  u32 x = __float_as_uint(f);
  return (u16)((x + 0x7fffu + ((x >> 16) & 1u)) >> 16);
}
static __device__ __forceinline__ void gload_lds16(const void* g, void* l) {
  __builtin_amdgcn_global_load_lds(
      (const __attribute__((address_space(1))) void*)g,
      (__attribute__((address_space(3))) void*)l, 16, 0, 0);
}

// ---------- prep: per-weight abs-mean (two-stage, deterministic) ----------
struct WMeta {
  const float* src;
  u16* dst;
  int N, K, Np, Kp, scaleIdx, blockStart;
};
struct PrepArgs { WMeta w[10]; };

__global__ __launch_bounds__(256)
void absmean_part(PrepArgs pa, double* __restrict__ partials)
{
  const int w = blockIdx.x >> 6;
  const int p = blockIdx.x & 63;
  const WMeta mw = pa.w[w];
  const long n = (long)mw.N * mw.K;
  const long chunk = (n + 63) >> 6;
  const long lo = (long)p * chunk;
  const long hi = min(n, lo + chunk);
  double sum = 0.0;
  for (long i = lo + threadIdx.x; i < hi; i += 256)
    sum += (double)fabsf(mw.src[i]);
  __shared__ double red[256];
  red[threadIdx.x] = sum;
  __syncthreads();
  for (int off = 128; off > 0; off >>= 1) {
    if (threadIdx.x < off) red[threadIdx.x] += red[threadIdx.x + off];
    __syncthreads();
  }
  if (threadIdx.x == 0) partials[blockIdx.x] = red[0];
}

__global__ __launch_bounds__(64)
void absmean_final(PrepArgs pa, const double* __restrict__ partials,
                   float* __restrict__ scales)
{
  const int w = threadIdx.x;
  if (w < 10) {
    double s = 0.0;
    #pragma unroll
    for (int i = 0; i < 64; ++i) s += partials[(w << 6) + i];
    const WMeta mw = pa.w[w];
    double m = s / (double)((long)mw.N * mw.K);
    scales[mw.scaleIdx] = (float)fmax(m, 1e-5);
  }
}

__global__ __launch_bounds__(256)
void ternarize_k(PrepArgs pa, const float* __restrict__ scales)
{
  const int b = blockIdx.x;
  int w = 0;
  #pragma unroll
  for (int i = 1; i < 10; ++i) if (b >= pa.w[i].blockStart) w = i;
  const WMeta mw = pa.w[w];
  const float inv = 1.0f / scales[mw.scaleIdx];
  const int tot = mw.Np * mw.Kp;
  int idx = (b - mw.blockStart) * 2048 + threadIdx.x * 8;
  #pragma unroll
  for (int j = 0; j < 8; ++j, ++idx) {
    if (idx < tot) {
      const int nn = idx / mw.Kp;
      const int kk = idx - nn * mw.Kp;
      float v = 0.f;
      if (nn < mw.N && kk < mw.K) {
        float t = rintf(mw.src[(size_t)nn * mw.K + kk] * inv);
        v = fminf(1.f, fmaxf(-1.f, t));
      }
      mw.dst[idx] = f2b(v);  // exact {-1,0,1}
    }
  }
}

// ---------- x (f32 [B][784]) -> bf16 padded [B][896] ----------
__global__ __launch_bounds__(256)
void convert_x(const float* __restrict__ x, u16* __restrict__ xb)
{
  const int s = blockIdx.x * 256 + threadIdx.x;   // B*112 vec8 slots
  const int row = s / 112;
  const int c8 = s - row * 112;
  u16x8 o = (u16x8)(u16)0;
  if (c8 < 98) {
    const float4* px = (const float4*)(x + (size_t)row * 784 + c8 * 8);
    float4 v0 = px[0], v1 = px[1];
    o[0] = f2b(v0.x); o[1] = f2b(v0.y); o[2] = f2b(v0.z); o[3] = f2b(v0.w);
    o[4] = f2b(v1.x); o[5] = f2b(v1.y); o[6] = f2b(v1.z); o[7] = f2b(v1.w);
  }
  *(u16x8*)(xb + (size_t)row * 896 + c8 * 8) = o;
}

// ---------- GEMM 256x256, BK=32, 8 waves (2Mx4N), 3-slot LDS, counted vmcnt ----------
// C[m][n] = act[m][k] * T[n][k].  Staging: global_load_lds w16, linear LDS dest,
// pre-swizzled global source; read applies same chunk-XOR (2-way banks only).
// Pipeline: stage(kt+2) -> vmcnt(8) guarantees stage(kt) landed (4 loads/thread
// per stage; outstanding after wait = stage(kt+1)+stage(kt+2) = 8). No
// __syncthreads in the K-loop (raw s_barrier; loads stay in flight 2 steps).
template<bool LRELU, bool SIGMOID, bool OUTBF16>
__global__ __launch_bounds__(512, 2)
void gemm256(const u16* __restrict__ A, const u16* __restrict__ Bw,
             void* __restrict__ Out, const float* __restrict__ sptr,
             int Kp, int ldOut, int Nstore)
{
  __shared__ __align__(16) u16 lds[3 * 16384];    // 3 slots x (A 16KB + B 16KB)
  const int tid = threadIdx.x;
  const int lane = tid & 63, wid = tid >> 6;
  const int wr = wid >> 2, wc = wid & 3;          // 2 x 4 wave grid
  const int m0 = blockIdx.x << 8, n0 = blockIdx.y << 8;
  const int NT = Kp >> 5;

  // stage addressing: dest linear (wave-uniform base + lane*16 implicit),
  // source pre-swizzled: chunk' = (tid&3) ^ ((tid>>3)&3)
  const int srow = tid >> 2;                                  // 0..127
  const int sk = (((tid & 3) ^ ((tid >> 3) & 3)) << 3);       // u16 k-offset
  const size_t gA0 = (size_t)(m0 + srow) * Kp + sk;
  const size_t gA1 = (size_t)(m0 + 128 + srow) * Kp + sk;
  const size_t gB0 = (size_t)(n0 + srow) * Kp + sk;
  const size_t gB1 = (size_t)(n0 + 128 + srow) * Kp + sk;
  const int ldst = wid << 9;                                  // wave-uniform u16 off

  auto stage = [&](int kt, int slot) {
    u16* base = lds + slot * 16384;
    const int ke = kt << 5;
    gload_lds16(A + gA0 + ke, base + ldst);
    gload_lds16(A + gA1 + ke, base + 4096 + ldst);
    gload_lds16(Bw + gB0 + ke, base + 8192 + ldst);
    gload_lds16(Bw + gB1 + ke, base + 12288 + ldst);
  };

  // read offsets: row*64B + swizzled 16B chunk; chunk-XOR is lane-only
  const int cs = (((lane >> 4) ^ ((lane >> 1) & 3)) << 4);
  int offA[8], offB[4];
  #pragma unroll
  for (int m = 0; m < 8; ++m)
    offA[m] = ((wr << 7) + (m << 4) + (lane & 15)) * 64 + cs;
  #pragma unroll
  for (int n = 0; n < 4; ++n)
    offB[n] = ((wc << 6) + (n << 4) + (lane & 15)) * 64 + cs + 16384;

  f32x4 acc[8][4] = {};
  stage(0, 0);
  stage(1, 1);
  int slot = 0;
  for (int kt = 0; kt < NT; ++kt) {
    // barrier 1: all waves done READING slot (kt+2)%3 (read at step kt-1)
    asm volatile("s_waitcnt lgkmcnt(0)" ::: "memory");
    __builtin_amdgcn_s_barrier();
    asm volatile("" ::: "memory");
    int st2 = slot + 2; if (st2 >= 3) st2 -= 3;
    if (kt + 2 < NT) {
      stage(kt + 2, st2);
      asm volatile("s_waitcnt vmcnt(8)" ::: "memory");   // stage(kt) landed
    } else if (kt + 1 < NT) {
      asm volatile("s_waitcnt vmcnt(4)" ::: "memory");
    } else {
      asm volatile("s_waitcnt vmcnt(0)" ::: "memory");
    }
    // barrier 2: every thread passed its vmcnt -> slot kt data visible to all
    __builtin_amdgcn_s_barrier();
    asm volatile("" ::: "memory");

    const char* lbase = (const char*)(lds + slot * 16384);
    bf16x8 av[8], bv[4];
    #pragma unroll
    for (int m = 0; m < 8; ++m) av[m] = *(const bf16x8*)(lbase + offA[m]);
    #pragma unroll
    for (int n = 0; n < 4; ++n) bv[n] = *(const bf16x8*)(lbase + offB[n]);
    __builtin_amdgcn_s_setprio(1);
    #pragma unroll
    for (int m = 0; m < 8; ++m)
      #pragma unroll
      for (int n = 0; n < 4; ++n)
        acc[m][n] = __builtin_amdgcn_mfma_f32_16x16x32_bf16(av[m], bv[n], acc[m][n], 0, 0, 0);
    __builtin_amdgcn_s_setprio(0);
    slot = (slot == 2) ? 0 : slot + 1;
  }

  // epilogue: D layout col=lane&15, row=(lane>>4)*4+reg [m89-verified]
  const float s = *sptr;
  #pragma unroll
  for (int n = 0; n < 4; ++n) {
    const int col = n0 + (wc << 6) + (n << 4) + (lane & 15);
    if (col >= Nstore) continue;
    #pragma unroll
    for (int m = 0; m < 8; ++m) {
      const int row0 = m0 + (wr << 7) + (m << 4) + ((lane >> 4) << 2);
      #pragma unroll
      for (int r = 0; r < 4; ++r) {
        float v = acc[m][n][r] * s;
        if (LRELU)   v = v >= 0.f ? v : 0.2f * v;
        if (SIGMOID) v = 1.f / (1.f + __expf(-v));
        if (OUTBF16) ((u16*)Out)[(size_t)(row0 + r) * ldOut + col] = f2b(v);
        else         ((float*)Out)[(size_t)(row0 + r) * ldOut + col] = v;
      }
    }
  }
}

// ---------- mid: h3 -> mean/logvar (to d_out), z = mean+logvar*eps, d1 act ----------
__global__ __launch_bounds__(256)
void mid_kernel(const u16* __restrict__ h3, const u16* __restrict__ wmulv,
                const u16* __restrict__ wd1, const float* __restrict__ eps,
                float* __restrict__ outMean, float* __restrict__ outLv,
                u16* __restrict__ hd1, const float* __restrict__ scales)
{
  __shared__ __align__(16) u16 wML[1024];   // [4][256]: mu0, mu1, lv0, lv1
  __shared__ u32 wD1s[256];                 // packed (t0,t1) per output n
  __shared__ float zz[64][2];
  const int tid = threadIdx.x;
  if (tid < 128) ((u16x8*)wML)[tid] = ((const u16x8*)wmulv)[tid];
  wD1s[tid] = ((const u32*)wd1)[tid];
  __syncthreads();
  const float smu = scales[3], slv = scales[4], sd1 = scales[5];
  const int rl = tid >> 2, q = tid & 3;
  const size_t row = (size_t)blockIdx.x * 64 + rl;
  float a0 = 0.f, a1 = 0.f, a2 = 0.f, a3 = 0.f;
  const u16* hrow = h3 + row * 256 + q * 64;
  #pragma unroll
  for (int k8 = 0; k8 < 8; ++k8) {
    u16x8 hv = *(const u16x8*)(hrow + k8 * 8);
    u16x8 w0 = *(const u16x8*)(wML +   0 + q * 64 + k8 * 8);
    u16x8 w1 = *(const u16x8*)(wML + 256 + q * 64 + k8 * 8);
    u16x8 w2 = *(const u16x8*)(wML + 512 + q * 64 + k8 * 8);
    u16x8 w3 = *(const u16x8*)(wML + 768 + q * 64 + k8 * 8);
    #pragma unroll
    for (int j = 0; j < 8; ++j) {
      const float hf = b2f(hv[j]);
      a0 += hf * b2f(w0[j]);
      a1 += hf * b2f(w1[j]);
      a2 += hf * b2f(w2[j]);
      a3 += hf * b2f(w3[j]);
    }
  }
  a0 += __shfl_xor(a0, 1); a0 += __shfl_xor(a0, 2);
  a1 += __shfl_xor(a1, 1); a1 += __shfl_xor(a1, 2);
  a2 += __shfl_xor(a2, 1); a2 += __shfl_xor(a2, 2);
  a3 += __shfl_xor(a3, 1); a3 += __shfl_xor(a3, 2);
  if (q == 0) {
    const float m0v = a0 * smu, m1v = a1 * smu;
    const float l0v = a2 * slv, l1v = a3 * slv;
    const float e0 = eps[row * 2], e1 = eps[row * 2 + 1];
    outMean[row * 2]     = m0v; outMean[row * 2 + 1] = m1v;
    outLv[row * 2]       = l0v; outLv[row * 2 + 1]   = l1v;
    zz[rl][0] = m0v + l0v * e0;
    zz[rl][1] = m1v + l1v * e1;
  }
  __syncthreads();
  const u32 wp = wD1s[tid];
  const float t0 = b2f((u16)(wp & 0xffffu));
  const float t1 = b2f((u16)(wp >> 16));
  const bool live = tid < 200;
  u16* ocol = hd1 + ((size_t)blockIdx.x * 64) * 256 + tid;
  #pragma unroll 4
  for (int it = 0; it < 64; ++it) {
    float v = live ? sd1 * (zz[it][0] * t0 + zz[it][1] * t1) : 0.f;
    v = v >= 0.f ? v : 0.2f * v;
    ocol[(size_t)it * 256] = f2b(v);
  }
}

// ---------- launch ----------
extern "C" void kernel_launch(void* const* d_in, const int* in_sizes, int n_in,
                              void* d_out, int out_size, void* d_ws, size_t ws_size,
                              hipStream_t stream)
{
  (void)in_sizes; (void)n_in; (void)out_size; (void)ws_size;
  const float* x   = (const float*)d_in[0];
  const float* eps = (const float*)d_in[1];
  float* out_f = (float*)d_out;

  float* scales = (float*)d_ws;                       // 16 floats @0
  u16* wb = (u16*)((char*)d_ws + 256);                // ternary weights (bf16, padded)
  // elem offsets (all Np%256==0 for GEMM layers, Kp%32==0)
  constexpr size_t E1 = 0;              // [512][896]
  constexpr size_t E2 = 458752;         // [512][512]
  constexpr size_t E3 = 720896;         // [256][512]
  constexpr size_t MULV = 851968;       // [4][256]
  constexpr size_t D1 = 852992;         // [256][2]
  constexpr size_t D2 = 853504;         // [512][256]
  constexpr size_t D3 = 984576;         // [512][512]
  constexpr size_t D4 = 1246720;        // [512][512]
  constexpr size_t D5 = 1508864;        // [1024][512]
  constexpr size_t WTOT = 2033152;
  u16* bufA = (u16*)((char*)d_ws + 256 + WTOT * 2);   // [B][896] max
  u16* bufB = (u16*)((char*)bufA + (size_t)65536 * 896 * 2);  // [B][512] max
  double* partials = (double*)bufA;                   // 640 doubles (pre-convert_x)

  PrepArgs pa;
  auto setw = [&](int i, int di, size_t off, int N, int K, int Np, int Kp, int bs) {
    pa.w[i] = WMeta{ (const float*)d_in[di], wb + off, N, K, Np, Kp, i, bs };
  };
  setw(0,  2, E1,        400, 784, 512, 896,   0);   // e1: 224 blocks
  setw(1,  3, E2,        400, 400, 512, 512, 224);   // e2: 128
  setw(2,  4, E3,        200, 400, 256, 512, 352);   // e3: 64
  setw(3,  5, MULV,        2, 200,   2, 256, 416);   // mu: 1
  setw(4,  6, MULV + 512,  2, 200,   2, 256, 417);   // lv: 1
  setw(5,  7, D1,        200,   2, 256,   2, 418);   // d1: 1
  setw(6,  8, D2,        400, 200, 512, 256, 419);   // d2: 64
  setw(7,  9, D3,        400, 400, 512, 512, 483);   // d3: 128
  setw(8, 10, D4,        400, 400, 512, 512, 611);   // d4: 128
  setw(9, 11, D5,        784, 400,1024, 512, 739);   // d5: 256 -> total 995

  absmean_part<<<640, 256, 0, stream>>>(pa, partials);
  absmean_final<<<1, 64, 0, stream>>>(pa, partials, scales);
  ternarize_k<<<995, 256, 0, stream>>>(pa, scales);
  convert_x<<<28672, 256, 0, stream>>>(x, bufA);      // x -> bufA [B][896]

  dim3 blk(512);
  // encoder
  gemm256<true , false, true ><<<dim3(256, 2), blk, 0, stream>>>(bufA, wb + E1, bufB, scales + 0, 896, 512, 512); // h1
  gemm256<true , false, true ><<<dim3(256, 2), blk, 0, stream>>>(bufB, wb + E2, bufA, scales + 1, 512, 512, 512); // h2
  gemm256<true , false, true ><<<dim3(256, 1), blk, 0, stream>>>(bufA, wb + E3, bufB, scales + 2, 512, 256, 256); // h3
  // mean/logvar/z/d1
  mid_kernel<<<1024, 256, 0, stream>>>(bufB, wb + MULV, wb + D1, eps,
                                       out_f + (size_t)65536 * 784,
                                       out_f + (size_t)65536 * 784 + 131072,
                                       bufA, scales);
  // decoder
  gemm256<true , false, true ><<<dim3(256, 2), blk, 0, stream>>>(bufA, wb + D2, bufB, scales + 6, 256, 512, 512); // d2
  gemm256<true , false, true ><<<dim3(256, 2), blk, 0, stream>>>(bufB, wb + D3, bufA, scales + 7, 512, 512, 512); // d3
  gemm256<true , false, true ><<<dim3(256, 2), blk, 0, stream>>>(bufA, wb + D4, bufB, scales + 8, 512, 512, 512); // d4
  gemm256<false, true , false><<<dim3(256, 4), blk, 0, stream>>>(bufB, wb + D5, (void*)out_f, scales + 9, 512, 784, 784); // x_hat
}

// Round 8
// 773.055 us; speedup vs baseline: 1.2115x; 1.2115x over previous
//
#include <hip/hip_runtime.h>

using u16 = unsigned short;
using u32 = unsigned int;

typedef __attribute__((ext_vector_type(8))) short bf16x8;   // 8 bf16 (MFMA frag)
typedef __attribute__((ext_vector_type(4))) float f32x4;    // MFMA acc
typedef __attribute__((ext_vector_type(8))) u16 u16x8;

// ---------- helpers ----------
static __device__ __forceinline__ float b2f(u16 u) {
  return __uint_as_float((u32)u << 16);
}
static __device__ __forceinline__ u16 f2b(float f) {  // RNE bf16
  u32 x = __float_as_uint(f);
  return (u16)((x + 0x7fffu + ((x >> 16) & 1u)) >> 16);
}
static __device__ __forceinline__ void gload_lds16(const void* g, void* l) {
  __builtin_amdgcn_global_load_lds(
      (const __attribute__((address_space(1))) void*)g,
      (__attribute__((address_space(3))) void*)l, 16, 0, 0);
}

// ---------- prep: per-weight abs-mean (two-stage, deterministic) ----------
struct WMeta {
  const float* src;
  u16* dst;
  int N, K, Np, Kp, scaleIdx, blockStart;
};
struct PrepArgs { WMeta w[10]; };

__global__ __launch_bounds__(256)
void absmean_part(PrepArgs pa, double* __restrict__ partials)
{
  const int w = blockIdx.x >> 6;
  const int p = blockIdx.x & 63;
  const WMeta mw = pa.w[w];
  const long n = (long)mw.N * mw.K;
  const long chunk = (n + 63) >> 6;
  const long lo = (long)p * chunk;
  const long hi = min(n, lo + chunk);
  double sum = 0.0;
  for (long i = lo + threadIdx.x; i < hi; i += 256)
    sum += (double)fabsf(mw.src[i]);
  __shared__ double red[256];
  red[threadIdx.x] = sum;
  __syncthreads();
  for (int off = 128; off > 0; off >>= 1) {
    if (threadIdx.x < off) red[threadIdx.x] += red[threadIdx.x + off];
    __syncthreads();
  }
  if (threadIdx.x == 0) partials[blockIdx.x] = red[0];
}

__global__ __launch_bounds__(64)
void absmean_final(PrepArgs pa, const double* __restrict__ partials,
                   float* __restrict__ scales)
{
  const int w = threadIdx.x;
  if (w < 10) {
    double s = 0.0;
    #pragma unroll
    for (int i = 0; i < 64; ++i) s += partials[(w << 6) + i];
    const WMeta mw = pa.w[w];
    double m = s / (double)((long)mw.N * mw.K);
    scales[mw.scaleIdx] = (float)fmax(m, 1e-5);
  }
}

__global__ __launch_bounds__(256)
void ternarize_k(PrepArgs pa, const float* __restrict__ scales)
{
  const int b = blockIdx.x;
  int w = 0;
  #pragma unroll
  for (int i = 1; i < 10; ++i) if (b >= pa.w[i].blockStart) w = i;
  const WMeta mw = pa.w[w];
  const float inv = 1.0f / scales[mw.scaleIdx];
  const int tot = mw.Np * mw.Kp;
  int idx = (b - mw.blockStart) * 2048 + threadIdx.x * 8;
  #pragma unroll
  for (int j = 0; j < 8; ++j, ++idx) {
    if (idx < tot) {
      const int nn = idx / mw.Kp;
      const int kk = idx - nn * mw.Kp;
      float v = 0.f;
      if (nn < mw.N && kk < mw.K) {
        float t = rintf(mw.src[(size_t)nn * mw.K + kk] * inv);
        v = fminf(1.f, fmaxf(-1.f, t));
      }
      mw.dst[idx] = f2b(v);  // exact {-1,0,1}
    }
  }
}

// ---------- x (f32 [B][784]) -> bf16 padded [B][896] ----------
__global__ __launch_bounds__(256)
void convert_x(const float* __restrict__ x, u16* __restrict__ xb)
{
  const int s = blockIdx.x * 256 + threadIdx.x;   // B*112 vec8 slots
  const int row = s / 112;
  const int c8 = s - row * 112;
  u16x8 o = (u16x8)(u16)0;
  if (c8 < 98) {
    const float4* px = (const float4*)(x + (size_t)row * 784 + c8 * 8);
    float4 v0 = px[0], v1 = px[1];
    o[0] = f2b(v0.x); o[1] = f2b(v0.y); o[2] = f2b(v0.z); o[3] = f2b(v0.w);
    o[4] = f2b(v1.x); o[5] = f2b(v1.y); o[6] = f2b(v1.z); o[7] = f2b(v1.w);
  }
  *(u16x8*)(xb + (size_t)row * 896 + c8 * 8) = o;
}

// ---------- GEMM 128(M)x256(N), BK=32, 8 waves (2Mx4N), 3-slot LDS, 2 blk/CU ----
// C[m][n] = act[m][k] * T[n][k].  Same verified addressing as R5: linear LDS
// dest (wave-uniform base), pre-swizzled global source chunk (tid&3)^((tid>>3)&3),
// read applies matching lane swizzle -> 2-way banks (free). 3 loads/thread/stage
// -> steady vmcnt(6) = 2 stages outstanding => stage(kt) landed. Raw s_barriers,
// no vmcnt(0) drain in loop. LDS 72KB -> 2 blocks/CU for latency overlap.
// Grid: x = N-tile (fast; consecutive blocks share A-panel), y = M-tile.
template<bool LRELU, bool SIGMOID, bool OUTBF16>
__global__ __launch_bounds__(512, 4)
void gemm128(const u16* __restrict__ A, const u16* __restrict__ Bw,
             void* __restrict__ Out, const float* __restrict__ sptr,
             int Kp, int ldOut, int Nstore)
{
  __shared__ __align__(16) u16 lds[3 * 12288];    // 3 slots x (A 8KB + B 16KB)
  const int tid = threadIdx.x;
  const int lane = tid & 63, wid = tid >> 6;
  const int wr = wid >> 2, wc = wid & 3;          // 2(M) x 4(N) wave grid

  // bijective XCD swizzle (nwg % 8 == 0 for all layers)
  const u32 bid = blockIdx.y * gridDim.x + blockIdx.x;
  const u32 cpx = (gridDim.x * gridDim.y) >> 3;
  const u32 wg = (bid & 7) * cpx + (bid >> 3);
  const int m0 = (int)(wg / gridDim.x) << 7;
  const int n0 = (int)(wg % gridDim.x) << 8;
  const int NT = Kp >> 5;

  // staging: thread t -> row t>>2, global 16B chunk (t&3)^((t>>3)&3)
  const int srow = tid >> 2;                                  // 0..127
  const int sk = (((tid & 3) ^ ((tid >> 3) & 3)) << 3);       // u16 k-offset
  const size_t gA0 = (size_t)(m0 + srow) * Kp + sk;
  const size_t gB0 = (size_t)(n0 + srow) * Kp + sk;
  const size_t gB1 = (size_t)(n0 + 128 + srow) * Kp + sk;
  const int ldst = wid << 9;                                  // wave-uniform u16 off

  auto stage = [&](int kt, int slot) {
    u16* base = lds + slot * 12288;
    const int ke = kt << 5;
    gload_lds16(A + gA0 + ke, base + ldst);                   // A [0,4096)
    gload_lds16(Bw + gB0 + ke, base + 4096 + ldst);           // B0 [4096,8192)
    gload_lds16(Bw + gB1 + ke, base + 8192 + ldst);           // B1 [8192,12288)
  };

  // read offsets: row*64B + swizzled 16B chunk (2-way bank alias only)
  const int cs = (((lane >> 4) ^ ((lane >> 1) & 3)) << 4);
  int offA[4], offB[4];
  #pragma unroll
  for (int m = 0; m < 4; ++m)
    offA[m] = ((wr << 6) + (m << 4) + (lane & 15)) * 64 + cs;
  #pragma unroll
  for (int n = 0; n < 4; ++n)
    offB[n] = ((wc << 6) + (n << 4) + (lane & 15)) * 64 + cs + 8192;

  f32x4 acc[4][4] = {};
  stage(0, 0);
  stage(1, 1);
  int slot = 0;
  for (int kt = 0; kt < NT; ++kt) {
    // barrier 1: all waves done READING the slot about to be overwritten
    asm volatile("s_waitcnt lgkmcnt(0)" ::: "memory");
    __builtin_amdgcn_s_barrier();
    asm volatile("" ::: "memory");
    int st2 = slot + 2; if (st2 >= 3) st2 -= 3;
    if (kt + 2 < NT) {
      stage(kt + 2, st2);
      asm volatile("s_waitcnt vmcnt(6)" ::: "memory");   // stage(kt) landed
    } else if (kt + 1 < NT) {
      asm volatile("s_waitcnt vmcnt(3)" ::: "memory");
    } else {
      asm volatile("s_waitcnt vmcnt(0)" ::: "memory");
    }
    // barrier 2: every thread passed its vmcnt -> slot kt visible to all
    __builtin_amdgcn_s_barrier();
    asm volatile("" ::: "memory");

    const char* lbase = (const char*)(lds + slot * 12288);
    bf16x8 av[4], bv[4];
    #pragma unroll
    for (int m = 0; m < 4; ++m) av[m] = *(const bf16x8*)(lbase + offA[m]);
    #pragma unroll
    for (int n = 0; n < 4; ++n) bv[n] = *(const bf16x8*)(lbase + offB[n]);
    __builtin_amdgcn_s_setprio(1);
    #pragma unroll
    for (int m = 0; m < 4; ++m)
      #pragma unroll
      for (int n = 0; n < 4; ++n)
        acc[m][n] = __builtin_amdgcn_mfma_f32_16x16x32_bf16(av[m], bv[n], acc[m][n], 0, 0, 0);
    __builtin_amdgcn_s_setprio(0);
    slot = (slot == 2) ? 0 : slot + 1;
  }

  // epilogue: D layout col=lane&15, row=(lane>>4)*4+reg [m89-verified]
  const float s = *sptr;
  #pragma unroll
  for (int n = 0; n < 4; ++n) {
    const int col = n0 + (wc << 6) + (n << 4) + (lane & 15);
    if (col >= Nstore) continue;
    #pragma unroll
    for (int m = 0; m < 4; ++m) {
      const int row0 = m0 + (wr << 6) + (m << 4) + ((lane >> 4) << 2);
      #pragma unroll
      for (int r = 0; r < 4; ++r) {
        float v = acc[m][n][r] * s;
        if (LRELU)   v = v >= 0.f ? v : 0.2f * v;
        if (SIGMOID) v = 1.f / (1.f + __expf(-v));
        if (OUTBF16) ((u16*)Out)[(size_t)(row0 + r) * ldOut + col] = f2b(v);
        else         ((float*)Out)[(size_t)(row0 + r) * ldOut + col] = v;
      }
    }
  }
}

// ---------- mid: h3 -> mean/logvar (to d_out), z = mean+logvar*eps, d1 act ----------
__global__ __launch_bounds__(256)
void mid_kernel(const u16* __restrict__ h3, const u16* __restrict__ wmulv,
                const u16* __restrict__ wd1, const float* __restrict__ eps,
                float* __restrict__ outMean, float* __restrict__ outLv,
                u16* __restrict__ hd1, const float* __restrict__ scales)
{
  __shared__ __align__(16) u16 wML[1024];   // [4][256]: mu0, mu1, lv0, lv1
  __shared__ u32 wD1s[256];                 // packed (t0,t1) per output n
  __shared__ float zz[64][2];
  const int tid = threadIdx.x;
  if (tid < 128) ((u16x8*)wML)[tid] = ((const u16x8*)wmulv)[tid];
  wD1s[tid] = ((const u32*)wd1)[tid];
  __syncthreads();
  const float smu = scales[3], slv = scales[4], sd1 = scales[5];
  const int rl = tid >> 2, q = tid & 3;
  const size_t row = (size_t)blockIdx.x * 64 + rl;
  float a0 = 0.f, a1 = 0.f, a2 = 0.f, a3 = 0.f;
  const u16* hrow = h3 + row * 256 + q * 64;
  #pragma unroll
  for (int k8 = 0; k8 < 8; ++k8) {
    u16x8 hv = *(const u16x8*)(hrow + k8 * 8);
    u16x8 w0 = *(const u16x8*)(wML +   0 + q * 64 + k8 * 8);
    u16x8 w1 = *(const u16x8*)(wML + 256 + q * 64 + k8 * 8);
    u16x8 w2 = *(const u16x8*)(wML + 512 + q * 64 + k8 * 8);
    u16x8 w3 = *(const u16x8*)(wML + 768 + q * 64 + k8 * 8);
    #pragma unroll
    for (int j = 0; j < 8; ++j) {
      const float hf = b2f(hv[j]);
      a0 += hf * b2f(w0[j]);
      a1 += hf * b2f(w1[j]);
      a2 += hf * b2f(w2[j]);
      a3 += hf * b2f(w3[j]);
    }
  }
  a0 += __shfl_xor(a0, 1); a0 += __shfl_xor(a0, 2);
  a1 += __shfl_xor(a1, 1); a1 += __shfl_xor(a1, 2);
  a2 += __shfl_xor(a2, 1); a2 += __shfl_xor(a2, 2);
  a3 += __shfl_xor(a3, 1); a3 += __shfl_xor(a3, 2);
  if (q == 0) {
    const float m0v = a0 * smu, m1v = a1 * smu;
    const float l0v = a2 * slv, l1v = a3 * slv;
    const float e0 = eps[row * 2], e1 = eps[row * 2 + 1];
    outMean[row * 2]     = m0v; outMean[row * 2 + 1] = m1v;
    outLv[row * 2]       = l0v; outLv[row * 2 + 1]   = l1v;
    zz[rl][0] = m0v + l0v * e0;
    zz[rl][1] = m1v + l1v * e1;
  }
  __syncthreads();
  const u32 wp = wD1s[tid];
  const float t0 = b2f((u16)(wp & 0xffffu));
  const float t1 = b2f((u16)(wp >> 16));
  const bool live = tid < 200;
  u16* ocol = hd1 + ((size_t)blockIdx.x * 64) * 256 + tid;
  #pragma unroll 4
  for (int it = 0; it < 64; ++it) {
    float v = live ? sd1 * (zz[it][0] * t0 + zz[it][1] * t1) : 0.f;
    v = v >= 0.f ? v : 0.2f * v;
    ocol[(size_t)it * 256] = f2b(v);
  }
}

// ---------- launch ----------
extern "C" void kernel_launch(void* const* d_in, const int* in_sizes, int n_in,
                              void* d_out, int out_size, void* d_ws, size_t ws_size,
                              hipStream_t stream)
{
  (void)in_sizes; (void)n_in; (void)out_size; (void)ws_size;
  const float* x   = (const float*)d_in[0];
  const float* eps = (const float*)d_in[1];
  float* out_f = (float*)d_out;

  float* scales = (float*)d_ws;                       // 16 floats @0
  u16* wb = (u16*)((char*)d_ws + 256);                // ternary weights (bf16, padded)
  // elem offsets (GEMM layers: Np%256==0, Kp%32==0)
  constexpr size_t E1 = 0;              // [512][896]
  constexpr size_t E2 = 458752;         // [512][512]
  constexpr size_t E3 = 720896;         // [256][512]
  constexpr size_t MULV = 851968;       // [4][256]
  constexpr size_t D1 = 852992;         // [256][2]
  constexpr size_t D2 = 853504;         // [512][256]
  constexpr size_t D3 = 984576;         // [512][512]
  constexpr size_t D4 = 1246720;        // [512][512]
  constexpr size_t D5 = 1508864;        // [1024][512]
  constexpr size_t WTOT = 2033152;
  u16* bufA = (u16*)((char*)d_ws + 256 + WTOT * 2);   // [B][896] max
  u16* bufB = (u16*)((char*)bufA + (size_t)65536 * 896 * 2);  // [B][512] max
  double* partials = (double*)bufA;                   // 640 doubles (pre-convert_x)

  PrepArgs pa;
  auto setw = [&](int i, int di, size_t off, int N, int K, int Np, int Kp, int bs) {
    pa.w[i] = WMeta{ (const float*)d_in[di], wb + off, N, K, Np, Kp, i, bs };
  };
  setw(0,  2, E1,        400, 784, 512, 896,   0);   // e1: 224 blocks
  setw(1,  3, E2,        400, 400, 512, 512, 224);   // e2: 128
  setw(2,  4, E3,        200, 400, 256, 512, 352);   // e3: 64
  setw(3,  5, MULV,        2, 200,   2, 256, 416);   // mu: 1
  setw(4,  6, MULV + 512,  2, 200,   2, 256, 417);   // lv: 1
  setw(5,  7, D1,        200,   2, 256,   2, 418);   // d1: 1
  setw(6,  8, D2,        400, 200, 512, 256, 419);   // d2: 64
  setw(7,  9, D3,        400, 400, 512, 512, 483);   // d3: 128
  setw(8, 10, D4,        400, 400, 512, 512, 611);   // d4: 128
  setw(9, 11, D5,        784, 400,1024, 512, 739);   // d5: 256 -> total 995

  absmean_part<<<640, 256, 0, stream>>>(pa, partials);
  absmean_final<<<1, 64, 0, stream>>>(pa, partials, scales);
  ternarize_k<<<995, 256, 0, stream>>>(pa, scales);
  convert_x<<<28672, 256, 0, stream>>>(x, bufA);      // x -> bufA [B][896]

  dim3 blk(512);
  // grid: x = N-tiles (fast -> A-panel reuse), y = M-tiles (65536/128 = 512)
  // encoder
  gemm128<true , false, true ><<<dim3(2, 512), blk, 0, stream>>>(bufA, wb + E1, bufB, scales + 0, 896, 512, 512); // h1
  gemm128<true , false, true ><<<dim3(2, 512), blk, 0, stream>>>(bufB, wb + E2, bufA, scales + 1, 512, 512, 512); // h2
  gemm128<true , false, true ><<<dim3(1, 512), blk, 0, stream>>>(bufA, wb + E3, bufB, scales + 2, 512, 256, 256); // h3
  // mean/logvar/z/d1
  mid_kernel<<<1024, 256, 0, stream>>>(bufB, wb + MULV, wb + D1, eps,
                                       out_f + (size_t)65536 * 784,
                                       out_f + (size_t)65536 * 784 + 131072,
                                       bufA, scales);
  // decoder
  gemm128<true , false, true ><<<dim3(2, 512), blk, 0, stream>>>(bufA, wb + D2, bufB, scales + 6, 256, 512, 512); // d2
  gemm128<true , false, true ><<<dim3(2, 512), blk, 0, stream>>>(bufB, wb + D3, bufA, scales + 7, 512, 512, 512); // d3
  gemm128<true , false, true ><<<dim3(2, 512), blk, 0, stream>>>(bufA, wb + D4, bufB, scales + 8, 512, 512, 512); // d4
  gemm128<false, true , false><<<dim3(4, 512), blk, 0, stream>>>(bufB, wb + D5, (void*)out_f, scales + 9, 512, 784, 784); // x_hat
}

// Round 11
// 770.084 us; speedup vs baseline: 1.2162x; 1.0039x over previous
//
#include <hip/hip_runtime.h>

using u16 = unsigned short;
using u32 = unsigned int;

typedef __attribute__((ext_vector_type(8))) short bf16x8;   // 8 bf16 (MFMA frag)
typedef __attribute__((ext_vector_type(4))) float f32x4;    // MFMA acc
typedef __attribute__((ext_vector_type(8))) u16 u16x8;

// ---------- helpers ----------
static __device__ __forceinline__ float b2f(u16 u) {
  return __uint_as_float((u32)u << 16);
}
static __device__ __forceinline__ u16 f2b(float f) {  // RNE bf16
  u32 x = __float_as_uint(f);
  return (u16)((x + 0x7fffu + ((x >> 16) & 1u)) >> 16);
}
static __device__ __forceinline__ void gload_lds16(const void* g, void* l) {
  __builtin_amdgcn_global_load_lds(
      (const __attribute__((address_space(1))) void*)g,
      (__attribute__((address_space(3))) void*)l, 16, 0, 0);
}

// ---------- prep: per-weight abs-mean (two-stage, deterministic) ----------
struct WMeta {
  const float* src;
  u16* dst;
  int N, K, Np, Kp, scaleIdx, blockStart;
};
struct PrepArgs { WMeta w[10]; };

__global__ __launch_bounds__(256)
void absmean_part(PrepArgs pa, double* __restrict__ partials)
{
  const int w = blockIdx.x >> 6;
  const int p = blockIdx.x & 63;
  const WMeta mw = pa.w[w];
  const long n = (long)mw.N * mw.K;
  const long chunk = (n + 63) >> 6;
  const long lo = (long)p * chunk;
  const long hi = min(n, lo + chunk);
  double sum = 0.0;
  for (long i = lo + threadIdx.x; i < hi; i += 256)
    sum += (double)fabsf(mw.src[i]);
  __shared__ double red[256];
  red[threadIdx.x] = sum;
  __syncthreads();
  for (int off = 128; off > 0; off >>= 1) {
    if (threadIdx.x < off) red[threadIdx.x] += red[threadIdx.x + off];
    __syncthreads();
  }
  if (threadIdx.x == 0) partials[blockIdx.x] = red[0];
}

__global__ __launch_bounds__(64)
void absmean_final(PrepArgs pa, const double* __restrict__ partials,
                   float* __restrict__ scales)
{
  const int w = threadIdx.x;
  if (w < 10) {
    double s = 0.0;
    #pragma unroll
    for (int i = 0; i < 64; ++i) s += partials[(w << 6) + i];
    const WMeta mw = pa.w[w];
    double m = s / (double)((long)mw.N * mw.K);
    scales[mw.scaleIdx] = (float)fmax(m, 1e-5);
  }
}

__global__ __launch_bounds__(256)
void ternarize_k(PrepArgs pa, const float* __restrict__ scales)
{
  const int b = blockIdx.x;
  int w = 0;
  #pragma unroll
  for (int i = 1; i < 10; ++i) if (b >= pa.w[i].blockStart) w = i;
  const WMeta mw = pa.w[w];
  const float inv = 1.0f / scales[mw.scaleIdx];
  const int tot = mw.Np * mw.Kp;
  int idx = (b - mw.blockStart) * 2048 + threadIdx.x * 8;
  #pragma unroll
  for (int j = 0; j < 8; ++j, ++idx) {
    if (idx < tot) {
      const int nn = idx / mw.Kp;
      const int kk = idx - nn * mw.Kp;
      float v = 0.f;
      if (nn < mw.N && kk < mw.K) {
        float t = rintf(mw.src[(size_t)nn * mw.K + kk] * inv);
        v = fminf(1.f, fmaxf(-1.f, t));
      }
      mw.dst[idx] = f2b(v);  // exact {-1,0,1}
    }
  }
}

// ---------- x (f32 [B][784]) -> bf16 padded [B][896] ----------
__global__ __launch_bounds__(256)
void convert_x(const float* __restrict__ x, u16* __restrict__ xb)
{
  const int s = blockIdx.x * 256 + threadIdx.x;   // B*112 vec8 slots
  const int row = s / 112;
  const int c8 = s - row * 112;
  u16x8 o = (u16x8)(u16)0;
  if (c8 < 98) {
    const float4* px = (const float4*)(x + (size_t)row * 784 + c8 * 8);
    float4 v0 = px[0], v1 = px[1];
    o[0] = f2b(v0.x); o[1] = f2b(v0.y); o[2] = f2b(v0.z); o[3] = f2b(v0.w);
    o[4] = f2b(v1.x); o[5] = f2b(v1.y); o[6] = f2b(v1.z); o[7] = f2b(v1.w);
  }
  *(u16x8*)(xb + (size_t)row * 896 + c8 * 8) = o;
}

// ---------- GEMM 128x128, BK=32, 8 waves (2Mx4N, 64x32/wave), 3-slot LDS ------
// 48KB LDS -> 3 blocks/CU (24 waves/CU) for latency overlap; launch_bounds(512,6)
// targets <=85 VGPR. Addressing identical family to R8 (verified): linear LDS
// dest (wave-uniform base), pre-swizzled global source chunk (tid&3)^((tid>>3)&3),
// matching lane-XOR on read -> 2-way banks only. 2 loads/thread/stage ->
// steady vmcnt(4) = 2 stages outstanding => stage(kt) landed. Raw s_barriers,
// no vmcnt(0) drain in the main loop.
// Grid: x = N-tile (fast; neighbors share A-panel), y = M-tile; XCD swizzle.
template<bool LRELU, bool SIGMOID, bool OUTBF16>
__global__ __launch_bounds__(512, 6)
void gemm_t(const u16* __restrict__ A, const u16* __restrict__ Bw,
            void* __restrict__ Out, const float* __restrict__ sptr,
            int Kp, int ldOut, int Nstore)
{
  __shared__ __align__(16) u16 lds[3 * 8192];     // 3 slots x (A 8KB + B 8KB)
  const int tid = threadIdx.x;
  const int lane = tid & 63, wid = tid >> 6;
  const int wr = wid >> 2, wc = wid & 3;          // 2(M) x 4(N); wave tile 64x32

  // bijective XCD swizzle (nwg % 8 == 0 for all layers)
  const u32 bid = blockIdx.y * gridDim.x + blockIdx.x;
  const u32 cpx = (gridDim.x * gridDim.y) >> 3;
  const u32 wg = (bid & 7) * cpx + (bid >> 3);
  const int m0 = (int)(wg / gridDim.x) << 7;
  const int n0 = (int)(wg % gridDim.x) << 7;
  const int NT = Kp >> 5;

  // staging: thread t -> row t>>2, global 16B chunk (t&3)^((t>>3)&3)
  const int srow = tid >> 2;                                  // 0..127
  const int sk = (((tid & 3) ^ ((tid >> 3) & 3)) << 3);       // u16 k-offset
  const size_t gA0 = (size_t)(m0 + srow) * Kp + sk;
  const size_t gB0 = (size_t)(n0 + srow) * Kp + sk;
  const int ldst = wid << 9;                                  // wave-uniform u16 off

  auto stage = [&](int kt, int slot) {
    u16* base = lds + slot * 8192;
    const int ke = kt << 5;
    gload_lds16(A + gA0 + ke, base + ldst);                   // A [0,4096) u16
    gload_lds16(Bw + gB0 + ke, base + 4096 + ldst);           // B [4096,8192) u16
  };

  // read offsets (bytes): row*64 + swizzled 16B chunk (2-way bank alias only)
  const int cs = (((lane >> 4) ^ ((lane >> 1) & 3)) << 4);
  int offA[4], offB[2];
  #pragma unroll
  for (int m = 0; m < 4; ++m)
    offA[m] = ((wr << 6) + (m << 4) + (lane & 15)) * 64 + cs;
  #pragma unroll
  for (int n = 0; n < 2; ++n)
    offB[n] = ((wc << 5) + (n << 4) + (lane & 15)) * 64 + cs + 8192;

  f32x4 acc[4][2] = {};
  stage(0, 0);
  stage(1, 1);
  int slot = 0;
  for (int kt = 0; kt < NT; ++kt) {
    // barrier 1: all waves done READING the slot about to be overwritten
    asm volatile("s_waitcnt lgkmcnt(0)" ::: "memory");
    __builtin_amdgcn_s_barrier();
    asm volatile("" ::: "memory");
    int st2 = slot + 2; if (st2 >= 3) st2 -= 3;
    if (kt + 2 < NT) {
      stage(kt + 2, st2);
      asm volatile("s_waitcnt vmcnt(4)" ::: "memory");   // stage(kt) landed
    } else if (kt + 1 < NT) {
      asm volatile("s_waitcnt vmcnt(2)" ::: "memory");
    } else {
      asm volatile("s_waitcnt vmcnt(0)" ::: "memory");
    }
    // barrier 2: every thread passed its vmcnt -> slot kt visible to all
    __builtin_amdgcn_s_barrier();
    asm volatile("" ::: "memory");

    const char* lbase = (const char*)(lds + slot * 8192);
    bf16x8 av[4], bv[2];
    #pragma unroll
    for (int m = 0; m < 4; ++m) av[m] = *(const bf16x8*)(lbase + offA[m]);
    #pragma unroll
    for (int n = 0; n < 2; ++n) bv[n] = *(const bf16x8*)(lbase + offB[n]);
    __builtin_amdgcn_s_setprio(1);
    #pragma unroll
    for (int m = 0; m < 4; ++m)
      #pragma unroll
      for (int n = 0; n < 2; ++n)
        acc[m][n] = __builtin_amdgcn_mfma_f32_16x16x32_bf16(av[m], bv[n], acc[m][n], 0, 0, 0);
    __builtin_amdgcn_s_setprio(0);
    slot = (slot == 2) ? 0 : slot + 1;
  }

  // epilogue: D layout col=lane&15, row=(lane>>4)*4+reg [m89-verified]
  const float s = *sptr;
  #pragma unroll
  for (int n = 0; n < 2; ++n) {
    const int col = n0 + (wc << 5) + (n << 4) + (lane & 15);
    if (col >= Nstore) continue;
    #pragma unroll
    for (int m = 0; m < 4; ++m) {
      const int row0 = m0 + (wr << 6) + (m << 4) + ((lane >> 4) << 2);
      #pragma unroll
      for (int r = 0; r < 4; ++r) {
        float v = acc[m][n][r] * s;
        if (LRELU)   v = v >= 0.f ? v : 0.2f * v;
        if (SIGMOID) v = 1.f / (1.f + __expf(-v));
        if (OUTBF16) ((u16*)Out)[(size_t)(row0 + r) * ldOut + col] = f2b(v);
        else         ((float*)Out)[(size_t)(row0 + r) * ldOut + col] = v;
      }
    }
  }
}

// ---------- mid: h3 -> mean/logvar (to d_out), z = mean+logvar*eps, d1 act ----------
__global__ __launch_bounds__(256)
void mid_kernel(const u16* __restrict__ h3, const u16* __restrict__ wmulv,
                const u16* __restrict__ wd1, const float* __restrict__ eps,
                float* __restrict__ outMean, float* __restrict__ outLv,
                u16* __restrict__ hd1, const float* __restrict__ scales)
{
  __shared__ __align__(16) u16 wML[1024];   // [4][256]: mu0, mu1, lv0, lv1
  __shared__ u32 wD1s[256];                 // packed (t0,t1) per output n
  __shared__ float zz[64][2];
  const int tid = threadIdx.x;
  if (tid < 128) ((u16x8*)wML)[tid] = ((const u16x8*)wmulv)[tid];
  wD1s[tid] = ((const u32*)wd1)[tid];
  __syncthreads();
  const float smu = scales[3], slv = scales[4], sd1 = scales[5];
  const int rl = tid >> 2, q = tid & 3;
  const size_t row = (size_t)blockIdx.x * 64 + rl;
  float a0 = 0.f, a1 = 0.f, a2 = 0.f, a3 = 0.f;
  const u16* hrow = h3 + row * 256 + q * 64;
  #pragma unroll
  for (int k8 = 0; k8 < 8; ++k8) {
    u16x8 hv = *(const u16x8*)(hrow + k8 * 8);
    u16x8 w0 = *(const u16x8*)(wML +   0 + q * 64 + k8 * 8);
    u16x8 w1 = *(const u16x8*)(wML + 256 + q * 64 + k8 * 8);
    u16x8 w2 = *(const u16x8*)(wML + 512 + q * 64 + k8 * 8);
    u16x8 w3 = *(const u16x8*)(wML + 768 + q * 64 + k8 * 8);
    #pragma unroll
    for (int j = 0; j < 8; ++j) {
      const float hf = b2f(hv[j]);
      a0 += hf * b2f(w0[j]);
      a1 += hf * b2f(w1[j]);
      a2 += hf * b2f(w2[j]);
      a3 += hf * b2f(w3[j]);
    }
  }
  a0 += __shfl_xor(a0, 1); a0 += __shfl_xor(a0, 2);
  a1 += __shfl_xor(a1, 1); a1 += __shfl_xor(a1, 2);
  a2 += __shfl_xor(a2, 1); a2 += __shfl_xor(a2, 2);
  a3 += __shfl_xor(a3, 1); a3 += __shfl_xor(a3, 2);
  if (q == 0) {
    const float m0v = a0 * smu, m1v = a1 * smu;
    const float l0v = a2 * slv, l1v = a3 * slv;
    const float e0 = eps[row * 2], e1 = eps[row * 2 + 1];
    outMean[row * 2]     = m0v; outMean[row * 2 + 1] = m1v;
    outLv[row * 2]       = l0v; outLv[row * 2 + 1]   = l1v;
    zz[rl][0] = m0v + l0v * e0;
    zz[rl][1] = m1v + l1v * e1;
  }
  __syncthreads();
  const u32 wp = wD1s[tid];
  const float t0 = b2f((u16)(wp & 0xffffu));
  const float t1 = b2f((u16)(wp >> 16));
  const bool live = tid < 200;
  u16* ocol = hd1 + ((size_t)blockIdx.x * 64) * 256 + tid;
  #pragma unroll 4
  for (int it = 0; it < 64; ++it) {
    float v = live ? sd1 * (zz[it][0] * t0 + zz[it][1] * t1) : 0.f;
    v = v >= 0.f ? v : 0.2f * v;
    ocol[(size_t)it * 256] = f2b(v);
  }
}

// ---------- launch ----------
extern "C" void kernel_launch(void* const* d_in, const int* in_sizes, int n_in,
                              void* d_out, int out_size, void* d_ws, size_t ws_size,
                              hipStream_t stream)
{
  (void)in_sizes; (void)n_in; (void)out_size; (void)ws_size;
  const float* x   = (const float*)d_in[0];
  const float* eps = (const float*)d_in[1];
  float* out_f = (float*)d_out;

  float* scales = (float*)d_ws;                       // 16 floats @0
  u16* wb = (u16*)((char*)d_ws + 256);                // ternary weights (bf16, padded)
  // elem offsets (GEMM layers: Np%128==0, Kp%32==0)
  constexpr size_t E1 = 0;              // [512][896]
  constexpr size_t E2 = 458752;         // [512][512]
  constexpr size_t E3 = 720896;         // [256][512]
  constexpr size_t MULV = 851968;       // [4][256]
  constexpr size_t D1 = 852992;         // [256][2]
  constexpr size_t D2 = 853504;         // [512][256]
  constexpr size_t D3 = 984576;         // [512][512]
  constexpr size_t D4 = 1246720;        // [512][512]
  constexpr size_t D5 = 1508864;        // [1024][512]
  constexpr size_t WTOT = 2033152;
  u16* bufA = (u16*)((char*)d_ws + 256 + WTOT * 2);   // [B][896] max
  u16* bufB = (u16*)((char*)bufA + (size_t)65536 * 896 * 2);  // [B][512] max
  double* partials = (double*)bufA;                   // 640 doubles (pre-convert_x)

  PrepArgs pa;
  auto setw = [&](int i, int di, size_t off, int N, int K, int Np, int Kp, int bs) {
    pa.w[i] = WMeta{ (const float*)d_in[di], wb + off, N, K, Np, Kp, i, bs };
  };
  setw(0,  2, E1,        400, 784, 512, 896,   0);   // e1: 224 blocks
  setw(1,  3, E2,        400, 400, 512, 512, 224);   // e2: 128
  setw(2,  4, E3,        200, 400, 256, 512, 352);   // e3: 64
  setw(3,  5, MULV,        2, 200,   2, 256, 416);   // mu: 1
  setw(4,  6, MULV + 512,  2, 200,   2, 256, 417);   // lv: 1
  setw(5,  7, D1,        200,   2, 256,   2, 418);   // d1: 1
  setw(6,  8, D2,        400, 200, 512, 256, 419);   // d2: 64
  setw(7,  9, D3,        400, 400, 512, 512, 483);   // d3: 128
  setw(8, 10, D4,        400, 400, 512, 512, 611);   // d4: 128
  setw(9, 11, D5,        784, 400,1024, 512, 739);   // d5: 256 -> total 995

  absmean_part<<<640, 256, 0, stream>>>(pa, partials);
  absmean_final<<<1, 64, 0, stream>>>(pa, partials, scales);
  ternarize_k<<<995, 256, 0, stream>>>(pa, scales);
  convert_x<<<28672, 256, 0, stream>>>(x, bufA);      // x -> bufA [B][896]

  dim3 blk(512);
  // grid: x = N-tiles (128-wide), y = M-tiles (65536/128 = 512)
  // encoder
  gemm_t<true , false, true ><<<dim3(4, 512), blk, 0, stream>>>(bufA, wb + E1, bufB, scales + 0, 896, 512, 512); // h1
  gemm_t<true , false, true ><<<dim3(4, 512), blk, 0, stream>>>(bufB, wb + E2, bufA, scales + 1, 512, 512, 512); // h2
  gemm_t<true , false, true ><<<dim3(2, 512), blk, 0, stream>>>(bufA, wb + E3, bufB, scales + 2, 512, 256, 256); // h3
  // mean/logvar/z/d1
  mid_kernel<<<1024, 256, 0, stream>>>(bufB, wb + MULV, wb + D1, eps,
                                       out_f + (size_t)65536 * 784,
                                       out_f + (size_t)65536 * 784 + 131072,
                                       bufA, scales);
  // decoder
  gemm_t<true , false, true ><<<dim3(4, 512), blk, 0, stream>>>(bufA, wb + D2, bufB, scales + 6, 256, 512, 512); // d2
  gemm_t<true , false, true ><<<dim3(4, 512), blk, 0, stream>>>(bufB, wb + D3, bufA, scales + 7, 512, 512, 512); // d3
  gemm_t<true , false, true ><<<dim3(4, 512), blk, 0, stream>>>(bufA, wb + D4, bufB, scales + 8, 512, 512, 512); // d4
  gemm_t<false, true , false><<<dim3(8, 512), blk, 0, stream>>>(bufB, wb + D5, (void*)out_f, scales + 9, 512, 784, 784); // x_hat
}

// Round 13
// 753.273 us; speedup vs baseline: 1.2433x; 1.0223x over previous
//
#include <hip/hip_runtime.h>

using u16 = unsigned short;
using u32 = unsigned int;

typedef __attribute__((ext_vector_type(8))) short bf16x8;   // 8 bf16 (MFMA frag)
typedef __attribute__((ext_vector_type(4))) float f32x4;    // MFMA acc
typedef __attribute__((ext_vector_type(8))) u16 u16x8;

// ---------- helpers ----------
static __device__ __forceinline__ float b2f(u16 u) {
  return __uint_as_float((u32)u << 16);
}
static __device__ __forceinline__ u16 f2b(float f) {  // RNE bf16
  u32 x = __float_as_uint(f);
  return (u16)((x + 0x7fffu + ((x >> 16) & 1u)) >> 16);
}
static __device__ __forceinline__ void gload_lds16(const void* g, void* l) {
  __builtin_amdgcn_global_load_lds(
      (const __attribute__((address_space(1))) void*)g,
      (__attribute__((address_space(3))) void*)l, 16, 0, 0);
}

// ---------- prep: per-weight abs-mean (two-stage, deterministic) ----------
struct WMeta {
  const float* src;
  u16* dst;
  int N, K, Np, Kp, scaleIdx, blockStart;
};
struct PrepArgs { WMeta w[10]; };

__global__ __launch_bounds__(256)
void absmean_part(PrepArgs pa, double* __restrict__ partials)
{
  const int w = blockIdx.x >> 6;
  const int p = blockIdx.x & 63;
  const WMeta mw = pa.w[w];
  const long n = (long)mw.N * mw.K;
  const long chunk = (n + 63) >> 6;
  const long lo = (long)p * chunk;
  const long hi = min(n, lo + chunk);
  double sum = 0.0;
  for (long i = lo + threadIdx.x; i < hi; i += 256)
    sum += (double)fabsf(mw.src[i]);
  __shared__ double red[256];
  red[threadIdx.x] = sum;
  __syncthreads();
  for (int off = 128; off > 0; off >>= 1) {
    if (threadIdx.x < off) red[threadIdx.x] += red[threadIdx.x + off];
    __syncthreads();
  }
  if (threadIdx.x == 0) partials[blockIdx.x] = red[0];
}

__global__ __launch_bounds__(64)
void absmean_final(PrepArgs pa, const double* __restrict__ partials,
                   float* __restrict__ scales)
{
  const int w = threadIdx.x;
  if (w < 10) {
    double s = 0.0;
    #pragma unroll
    for (int i = 0; i < 64; ++i) s += partials[(w << 6) + i];
    const WMeta mw = pa.w[w];
    double m = s / (double)((long)mw.N * mw.K);
    scales[mw.scaleIdx] = (float)fmax(m, 1e-5);
  }
}

__global__ __launch_bounds__(256)
void ternarize_k(PrepArgs pa, const float* __restrict__ scales)
{
  const int b = blockIdx.x;
  int w = 0;
  #pragma unroll
  for (int i = 1; i < 10; ++i) if (b >= pa.w[i].blockStart) w = i;
  const WMeta mw = pa.w[w];
  const float inv = 1.0f / scales[mw.scaleIdx];
  const int tot = mw.Np * mw.Kp;
  int idx = (b - mw.blockStart) * 2048 + threadIdx.x * 8;
  #pragma unroll
  for (int j = 0; j < 8; ++j, ++idx) {
    if (idx < tot) {
      const int nn = idx / mw.Kp;
      const int kk = idx - nn * mw.Kp;
      float v = 0.f;
      if (nn < mw.N && kk < mw.K) {
        float t = rintf(mw.src[(size_t)nn * mw.K + kk] * inv);
        v = fminf(1.f, fmaxf(-1.f, t));
      }
      mw.dst[idx] = f2b(v);  // exact {-1,0,1}
    }
  }
}

// ---------- x (f32 [B][784]) -> bf16 padded [B][896] ----------
__global__ __launch_bounds__(256)
void convert_x(const float* __restrict__ x, u16* __restrict__ xb)
{
  const int s = blockIdx.x * 256 + threadIdx.x;   // B*112 vec8 slots
  const int row = s / 112;
  const int c8 = s - row * 112;
  u16x8 o = (u16x8)(u16)0;
  if (c8 < 98) {
    const float4* px = (const float4*)(x + (size_t)row * 784 + c8 * 8);
    float4 v0 = px[0], v1 = px[1];
    o[0] = f2b(v0.x); o[1] = f2b(v0.y); o[2] = f2b(v0.z); o[3] = f2b(v0.w);
    o[4] = f2b(v1.x); o[5] = f2b(v1.y); o[6] = f2b(v1.z); o[7] = f2b(v1.w);
  }
  *(u16x8*)(xb + (size_t)row * 896 + c8 * 8) = o;
}

// ---------- GEMM 256x256, BK=64, 8 waves, 8-phase interleave (T2+T3+T4+T5) ----
// Per K-tile: 4 quadrant-phases (qm,qn); phase reads ONLY A-half qm, B-half qn.
// Stage order per tile [A0,B0,B1,A1], 1 half (2 gload_lds) per phase, into the
// other buffer. Provable vmcnt ledger: phases 1-3 vmcnt(6), phase 4 none; last
// tile drains 4 -> 2 -> 0 (matches the m201 template epilogue). One s_barrier
// per phase (after vmcnt) makes all waves' staged loads visible; slot-overwrite
// gaps are >=3 barrier-separated phases. Swizzle: LDS(row,c)=global c^(row&7),
// linear gload_lds dest + pre-swizzled source; b128 reads hit the 8-cyc bank
// floor (conflict-free). 128KB LDS -> 1 block/CU.
template<bool LRELU, bool SIGMOID, bool OUTBF16>
__global__ __launch_bounds__(512, 2)
void gemm8p(const u16* __restrict__ A, const u16* __restrict__ Bw,
            void* __restrict__ Out, const float* __restrict__ sptr,
            int Kp, int ldOut, int Nstore)
{
  __shared__ __align__(16) u16 lds[2 * 4 * 8192];   // 128 KB: buf x {A0,A1,B0,B1}
  const int tid = threadIdx.x;
  const int lane = tid & 63, wid = tid >> 6;
  const int wr = wid >> 2, wc = wid & 3;            // 2x4 waves over 128x128 quadrant

  // bijective XCD swizzle (nwg % 8 == 0 for all layers)
  const u32 bid = blockIdx.y * gridDim.x + blockIdx.x;
  const u32 cpx = (gridDim.x * gridDim.y) >> 3;
  const u32 wg = (bid & 7) * cpx + (bid >> 3);
  const int m0 = (int)(wg / gridDim.x) << 8;
  const int n0 = (int)(wg % gridDim.x) << 8;
  const int NT = Kp >> 6;

  // staging: thread t -> row t>>3 (+64 for 2nd load), chunk (t&7)^(row&7)
  const int srow = tid >> 3;                                  // 0..63
  const int sk = (((tid & 7) ^ (srow & 7)) << 3);             // u16 offset
  const int ldst = wid << 9;                                  // u16, wave-uniform
  auto stage_half = [&](int tau, int b, int s) {
    const u16* src = (s < 2) ? A : Bw;
    const int rbase = ((s < 2) ? m0 : n0) + ((s & 1) << 7) + srow;
    const size_t kb = ((size_t)tau << 6) + sk;
    u16* d = lds + (b << 15) + (s << 13) + ldst;
    gload_lds16(src + (size_t)rbase * Kp + kb, d);
    gload_lds16(src + (size_t)(rbase + 64) * Kp + kb, d + 4096);
  };

  // read bases (bytes within a 16KB half-slot); row&7 == lane&7 for all frags
  const int rlaneA = (wr << 6) + (lane & 15);   // row in A-half (64-row wave span)
  const int rlaneB = (wc << 5) + (lane & 15);   // row in B-half (32-row wave span)
  const int swz0 = (((lane >> 4)) ^ (lane & 7)) << 4;        // kk=0 chunk byte-off
  const int swz1 = ((4 + (lane >> 4)) ^ (lane & 7)) << 4;    // kk=1
  const int baseA0 = rlaneA * 128 + swz0, baseA1 = rlaneA * 128 + swz1;
  const int baseB0 = rlaneB * 128 + swz0, baseB1 = rlaneB * 128 + swz1;

  f32x4 acc[8][4] = {};

  // prologue: tile 0, ledger order A0,B0,B1,A1
  stage_half(0, 0, 0);
  stage_half(0, 0, 2);
  stage_half(0, 0, 3);
  stage_half(0, 0, 1);

  for (int t = 0; t < NT; ++t) {
    const int pb = t & 1;
    const bool pref = (t + 1 < NT);
    const int sb = pb ^ 1;

#define GPHASE(QM, QN, SSLOT, WMAIN, WLAST)                                     \
    {                                                                           \
      if (pref) {                                                               \
        stage_half(t + 1, sb, SSLOT);                                           \
        if ((WMAIN) >= 0)                                                       \
          asm volatile("s_waitcnt vmcnt(%0)" :: "i"(WMAIN) : "memory");         \
      } else {                                                                  \
        if ((WLAST) >= 0)                                                       \
          asm volatile("s_waitcnt vmcnt(%0)" :: "i"(WLAST) : "memory");         \
      }                                                                         \
      __builtin_amdgcn_s_barrier();                                             \
      asm volatile("" ::: "memory");                                            \
      const char* pA = (const char*)(lds + (pb << 15) + ((QM) << 13));          \
      const char* pB = (const char*)(lds + (pb << 15) + ((2 + (QN)) << 13));    \
      bf16x8 av[4][2], bv[2][2];                                                \
      _Pragma("unroll")                                                         \
      for (int mf = 0; mf < 4; ++mf) {                                          \
        av[mf][0] = *(const bf16x8*)(pA + baseA0 + (mf << 11));                 \
        av[mf][1] = *(const bf16x8*)(pA + baseA1 + (mf << 11));                 \
      }                                                                         \
      _Pragma("unroll")                                                         \
      for (int nf = 0; nf < 2; ++nf) {                                          \
        bv[nf][0] = *(const bf16x8*)(pB + baseB0 + (nf << 11));                 \
        bv[nf][1] = *(const bf16x8*)(pB + baseB1 + (nf << 11));                 \
      }                                                                         \
      __builtin_amdgcn_s_setprio(1);                                            \
      _Pragma("unroll")                                                         \
      for (int mf = 0; mf < 4; ++mf)                                            \
        _Pragma("unroll")                                                       \
        for (int nf = 0; nf < 2; ++nf) {                                        \
          acc[((QM)<<2)+mf][((QN)<<1)+nf] =                                     \
            __builtin_amdgcn_mfma_f32_16x16x32_bf16(av[mf][0], bv[nf][0],       \
                acc[((QM)<<2)+mf][((QN)<<1)+nf], 0, 0, 0);                      \
          acc[((QM)<<2)+mf][((QN)<<1)+nf] =                                     \
            __builtin_amdgcn_mfma_f32_16x16x32_bf16(av[mf][1], bv[nf][1],       \
                acc[((QM)<<2)+mf][((QN)<<1)+nf], 0, 0, 0);                      \
        }                                                                       \
      __builtin_amdgcn_s_setprio(0);                                            \
    }

    GPHASE(0, 0, 0, 6, 4)   // needs A0,B0 of tile t
    GPHASE(0, 1, 2, 6, 2)   // needs B1
    GPHASE(1, 0, 3, 6, 0)   // needs A1
    GPHASE(1, 1, 1, -1, -1) // all resident
#undef GPHASE
  }

  // epilogue: D layout col=lane&15, row=(lane>>4)*4+reg [m89-verified]
  const float s = *sptr;
  #pragma unroll
  for (int qn = 0; qn < 2; ++qn)
  #pragma unroll
  for (int nf = 0; nf < 2; ++nf) {
    const int col = n0 + (qn << 7) + (wc << 5) + (nf << 4) + (lane & 15);
    if (col >= Nstore) continue;
    #pragma unroll
    for (int qm = 0; qm < 2; ++qm)
    #pragma unroll
    for (int mf = 0; mf < 4; ++mf) {
      const int row0 = m0 + (qm << 7) + (wr << 6) + (mf << 4) + ((lane >> 4) << 2);
      const f32x4 a = acc[(qm << 2) + mf][(qn << 1) + nf];
      #pragma unroll
      for (int r = 0; r < 4; ++r) {
        float v = a[r] * s;
        if (LRELU)   v = v >= 0.f ? v : 0.2f * v;
        if (SIGMOID) v = 1.f / (1.f + __expf(-v));
        if (OUTBF16) ((u16*)Out)[(size_t)(row0 + r) * ldOut + col] = f2b(v);
        else         ((float*)Out)[(size_t)(row0 + r) * ldOut + col] = v;
      }
    }
  }
}

// ---------- mid: h3 -> mean/logvar (to d_out), z = mean+logvar*eps, d1 act ----------
__global__ __launch_bounds__(256)
void mid_kernel(const u16* __restrict__ h3, const u16* __restrict__ wmulv,
                const u16* __restrict__ wd1, const float* __restrict__ eps,
                float* __restrict__ outMean, float* __restrict__ outLv,
                u16* __restrict__ hd1, const float* __restrict__ scales)
{
  __shared__ __align__(16) u16 wML[1024];   // [4][256]: mu0, mu1, lv0, lv1
  __shared__ u32 wD1s[256];                 // packed (t0,t1) per output n
  __shared__ float zz[64][2];
  const int tid = threadIdx.x;
  if (tid < 128) ((u16x8*)wML)[tid] = ((const u16x8*)wmulv)[tid];
  wD1s[tid] = ((const u32*)wd1)[tid];
  __syncthreads();
  const float smu = scales[3], slv = scales[4], sd1 = scales[5];
  const int rl = tid >> 2, q = tid & 3;
  const size_t row = (size_t)blockIdx.x * 64 + rl;
  float a0 = 0.f, a1 = 0.f, a2 = 0.f, a3 = 0.f;
  const u16* hrow = h3 + row * 256 + q * 64;
  #pragma unroll
  for (int k8 = 0; k8 < 8; ++k8) {
    u16x8 hv = *(const u16x8*)(hrow + k8 * 8);
    u16x8 w0 = *(const u16x8*)(wML +   0 + q * 64 + k8 * 8);
    u16x8 w1 = *(const u16x8*)(wML + 256 + q * 64 + k8 * 8);
    u16x8 w2 = *(const u16x8*)(wML + 512 + q * 64 + k8 * 8);
    u16x8 w3 = *(const u16x8*)(wML + 768 + q * 64 + k8 * 8);
    #pragma unroll
    for (int j = 0; j < 8; ++j) {
      const float hf = b2f(hv[j]);
      a0 += hf * b2f(w0[j]);
      a1 += hf * b2f(w1[j]);
      a2 += hf * b2f(w2[j]);
      a3 += hf * b2f(w3[j]);
    }
  }
  a0 += __shfl_xor(a0, 1); a0 += __shfl_xor(a0, 2);
  a1 += __shfl_xor(a1, 1); a1 += __shfl_xor(a1, 2);
  a2 += __shfl_xor(a2, 1); a2 += __shfl_xor(a2, 2);
  a3 += __shfl_xor(a3, 1); a3 += __shfl_xor(a3, 2);
  if (q == 0) {
    const float m0v = a0 * smu, m1v = a1 * smu;
    const float l0v = a2 * slv, l1v = a3 * slv;
    const float e0 = eps[row * 2], e1 = eps[row * 2 + 1];
    outMean[row * 2]     = m0v; outMean[row * 2 + 1] = m1v;
    outLv[row * 2]       = l0v; outLv[row * 2 + 1]   = l1v;
    zz[rl][0] = m0v + l0v * e0;
    zz[rl][1] = m1v + l1v * e1;
  }
  __syncthreads();
  const u32 wp = wD1s[tid];
  const float t0 = b2f((u16)(wp & 0xffffu));
  const float t1 = b2f((u16)(wp >> 16));
  const bool live = tid < 200;
  u16* ocol = hd1 + ((size_t)blockIdx.x * 64) * 256 + tid;
  #pragma unroll 4
  for (int it = 0; it < 64; ++it) {
    float v = live ? sd1 * (zz[it][0] * t0 + zz[it][1] * t1) : 0.f;
    v = v >= 0.f ? v : 0.2f * v;
    ocol[(size_t)it * 256] = f2b(v);
  }
}

// ---------- launch ----------
extern "C" void kernel_launch(void* const* d_in, const int* in_sizes, int n_in,
                              void* d_out, int out_size, void* d_ws, size_t ws_size,
                              hipStream_t stream)
{
  (void)in_sizes; (void)n_in; (void)out_size; (void)ws_size;
  const float* x   = (const float*)d_in[0];
  const float* eps = (const float*)d_in[1];
  float* out_f = (float*)d_out;

  float* scales = (float*)d_ws;                       // 16 floats @0
  u16* wb = (u16*)((char*)d_ws + 256);                // ternary weights (bf16, padded)
  // elem offsets (GEMM layers: Np%256==0, Kp%64==0)
  constexpr size_t E1 = 0;              // [512][896]
  constexpr size_t E2 = 458752;         // [512][512]
  constexpr size_t E3 = 720896;         // [256][512]
  constexpr size_t MULV = 851968;       // [4][256]
  constexpr size_t D1 = 852992;         // [256][2]
  constexpr size_t D2 = 853504;         // [512][256]
  constexpr size_t D3 = 984576;         // [512][512]
  constexpr size_t D4 = 1246720;        // [512][512]
  constexpr size_t D5 = 1508864;        // [1024][512]
  constexpr size_t WTOT = 2033152;
  u16* bufA = (u16*)((char*)d_ws + 256 + WTOT * 2);   // [B][896] max
  u16* bufB = (u16*)((char*)bufA + (size_t)65536 * 896 * 2);  // [B][512] max
  double* partials = (double*)bufA;                   // 640 doubles (pre-convert_x)

  PrepArgs pa;
  auto setw = [&](int i, int di, size_t off, int N, int K, int Np, int Kp, int bs) {
    pa.w[i] = WMeta{ (const float*)d_in[di], wb + off, N, K, Np, Kp, i, bs };
  };
  setw(0,  2, E1,        400, 784, 512, 896,   0);   // e1: 224 blocks
  setw(1,  3, E2,        400, 400, 512, 512, 224);   // e2: 128
  setw(2,  4, E3,        200, 400, 256, 512, 352);   // e3: 64
  setw(3,  5, MULV,        2, 200,   2, 256, 416);   // mu: 1
  setw(4,  6, MULV + 512,  2, 200,   2, 256, 417);   // lv: 1
  setw(5,  7, D1,        200,   2, 256,   2, 418);   // d1: 1
  setw(6,  8, D2,        400, 200, 512, 256, 419);   // d2: 64
  setw(7,  9, D3,        400, 400, 512, 512, 483);   // d3: 128
  setw(8, 10, D4,        400, 400, 512, 512, 611);   // d4: 128
  setw(9, 11, D5,        784, 400,1024, 512, 739);   // d5: 256 -> total 995

  absmean_part<<<640, 256, 0, stream>>>(pa, partials);
  absmean_final<<<1, 64, 0, stream>>>(pa, partials, scales);
  ternarize_k<<<995, 256, 0, stream>>>(pa, scales);
  convert_x<<<28672, 256, 0, stream>>>(x, bufA);      // x -> bufA [B][896]

  dim3 blk(512);
  // grid: x = N-tiles (256-wide, fast -> A-panel reuse), y = M-tiles (65536/256 = 256)
  // encoder
  gemm8p<true , false, true ><<<dim3(2, 256), blk, 0, stream>>>(bufA, wb + E1, bufB, scales + 0, 896, 512, 512); // h1
  gemm8p<true , false, true ><<<dim3(2, 256), blk, 0, stream>>>(bufB, wb + E2, bufA, scales + 1, 512, 512, 512); // h2
  gemm8p<true , false, true ><<<dim3(1, 256), blk, 0, stream>>>(bufA, wb + E3, bufB, scales + 2, 512, 256, 256); // h3
  // mean/logvar/z/d1
  mid_kernel<<<1024, 256, 0, stream>>>(bufB, wb + MULV, wb + D1, eps,
                                       out_f + (size_t)65536 * 784,
                                       out_f + (size_t)65536 * 784 + 131072,
                                       bufA, scales);
  // decoder
  gemm8p<true , false, true ><<<dim3(2, 256), blk, 0, stream>>>(bufA, wb + D2, bufB, scales + 6, 256, 512, 512); // d2
  gemm8p<true , false, true ><<<dim3(2, 256), blk, 0, stream>>>(bufB, wb + D3, bufA, scales + 7, 512, 512, 512); // d3
  gemm8p<true , false, true ><<<dim3(2, 256), blk, 0, stream>>>(bufA, wb + D4, bufB, scales + 8, 512, 512, 512); // d4
  gemm8p<false, true , false><<<dim3(4, 256), blk, 0, stream>>>(bufB, wb + D5, (void*)out_f, scales + 9, 512, 784, 784); // x_hat
}